// Round 8
// baseline (146.133 us; speedup 1.0000x reference)
//
#include <hip/hip_runtime.h>

typedef unsigned short u16;
typedef __bf16 bf16x8 __attribute__((ext_vector_type(8)));
typedef float  f32x16 __attribute__((ext_vector_type(16)));

__device__ __forceinline__ u16 f2bf(float f) {
    union { float f; unsigned u; } v; v.f = f;
    return (u16)((v.u + 0x7fffu + ((v.u >> 16) & 1u)) >> 16);
}

#define GLD16(gsrc, ldst) \
    __builtin_amdgcn_global_load_lds( \
        (const __attribute__((address_space(1))) void*)(gsrc), \
        (__attribute__((address_space(3))) void*)(ldst), 16, 0, 0)

// ---------------------------------------------------------------------------
// 1) s_raw[b][c] = w[b] @ mod_w[c] + mod_b[c]
// ---------------------------------------------------------------------------
__global__ __launch_bounds__(256) void lin_kernel(
    const float* __restrict__ w, const float* __restrict__ mod_w,
    const float* __restrict__ mod_b, float* __restrict__ s_raw)
{
    int gw = (blockIdx.x * 256 + threadIdx.x) >> 6;
    int lane = threadIdx.x & 63;
    int b = gw >> 9, c = gw & 511;
    const float* wr = w + b * 512;
    const float* mr = mod_w + (size_t)c * 512;
    float a = 0.f;
#pragma unroll
    for (int i = 0; i < 8; ++i)
        a = fmaf(wr[lane + i * 64], mr[lane + i * 64], a);
    for (int off = 32; off; off >>= 1) a += __shfl_down(a, off);
    if (!lane) s_raw[gw] = a + mod_b[c];
}

// ---------------------------------------------------------------------------
// 2) s_eff = LeakyReLU(LN(s_raw)) * scale
// ---------------------------------------------------------------------------
__global__ __launch_bounds__(512) void norm_kernel(
    const float* __restrict__ s_raw, const float* __restrict__ ln_g,
    const float* __restrict__ ln_b, const float* __restrict__ scale,
    float* __restrict__ s_eff)
{
    int b = blockIdx.x, c = threadIdx.x;
    __shared__ float rs[512], rq[512];
    float s = s_raw[b * 512 + c];
    rs[c] = s; rq[c] = s * s;
    __syncthreads();
    for (int off = 256; off; off >>= 1) {
        if (c < off) { rs[c] += rs[c + off]; rq[c] += rq[c + off]; }
        __syncthreads();
    }
    float mean = rs[0] * (1.f / 512.f);
    float var  = rq[0] * (1.f / 512.f) - mean * mean;
    float sn = (s - mean) * rsqrtf(var + 1e-5f) * ln_g[c] + ln_b[c];
    sn = sn >= 0.f ? sn : 0.2f * sn;
    s_eff[b * 512 + c] = sn * scale[c];
}

// ---------------------------------------------------------------------------
// 3) wsq[co][ci] = sum_p weight^2 ; wbfT[(p*64+cg)*512*8 + co*8 + cj] = bf16(w)
// ---------------------------------------------------------------------------
__global__ __launch_bounds__(256) void wsq_kernel(
    const float* __restrict__ weight, float* __restrict__ wsq, u16* __restrict__ wbfT)
{
    int idx = blockIdx.x * 256 + threadIdx.x;      // co*512+ci
    int co = idx >> 9, ci = idx & 511;
    int cg = ci >> 3, cj = ci & 7;
    const float* wp = weight + (size_t)idx * 9;
    float s = 0.f;
#pragma unroll
    for (int p = 0; p < 9; ++p) {
        float v = wp[p];
        s += v * v;
        wbfT[((size_t)(p * 64 + cg) * 512 + co) * 8 + cj] = f2bf(v);
    }
    wsq[idx] = s;
}

// ---------------------------------------------------------------------------
// 4) xs[b][h][w][c] (NHWC bf16) = bf16(x[b][c][h][w] * s_eff[b][c])
// ---------------------------------------------------------------------------
__global__ __launch_bounds__(256) void xs_kernel(
    const float* __restrict__ x, const float* __restrict__ s_eff,
    u16* __restrict__ xs)
{
    const int bh = blockIdx.x;
    const int b = bh >> 5, h = bh & 31;
    __shared__ float tile[64][33];
    for (int c0 = 0; c0 < 512; c0 += 64) {
        if (c0) __syncthreads();
        for (int idx = threadIdx.x; idx < 2048; idx += 256) {
            int c = idx >> 5, ww = idx & 31;
            tile[c][ww] = x[(((size_t)b * 512 + c0 + c) * 32 + h) * 32 + ww]
                          * s_eff[b * 512 + c0 + c];
        }
        __syncthreads();
        for (int idx = threadIdx.x; idx < 2048; idx += 256) {
            int ww = idx >> 6, c = idx & 63;
            xs[((b * 32 + h) * 32 + ww) * 512 + c0 + c] = f2bf(tile[c][ww]);
        }
    }
}

// ---------------------------------------------------------------------------
// 5) dsc[b][o] = rsqrt(sum_i s_eff[b][i]^2 * wsq[o][i] + 1e-8)
// ---------------------------------------------------------------------------
__global__ __launch_bounds__(256) void dsc_kernel(
    const float* __restrict__ s_eff, const float* __restrict__ wsq,
    float* __restrict__ dsc)
{
    int gw = (blockIdx.x * 256 + threadIdx.x) >> 6;
    int lane = threadIdx.x & 63;
    int b = gw >> 9, co = gw & 511;
    float a = 0.f;
#pragma unroll
    for (int i = 0; i < 8; ++i) {
        int cin = lane + i * 64;
        float se = s_eff[b * 512 + cin];
        a += se * se * wsq[co * 512 + cin];
    }
    for (int off = 32; off; off >>= 1) a += __shfl_down(a, off);
    if (!lane) dsc[gw] = rsqrtf(a + 1e-8f);
}

// ---------------------------------------------------------------------------
// 6) zero page for halo OOB lanes
// ---------------------------------------------------------------------------
__global__ void zfill_kernel(float* p) { p[threadIdx.x] = 0.f; }

// ---------------------------------------------------------------------------
// 7) conv, halo-restage, 4 blocks/CU (16 waves/CU = 4/SIMD) for latency hiding.
//    Grid 1024 = 2 mt (XCD-parity-pinned) x 512 single-row strips (b, h).
//    Block 256 thr = 4 M-waves, wave 64 co x 32 px, BM=256, BN=32.
//    Per 32-cin round: stage halo [3][34][32] once (6528 B, dbuf), 9 taps.
//    A (global) and B (LDS) fragments prefetched one pos ahead (ping-pong).
//    Counted-vmcnt barrier; setprio(1) around MFMA cluster (T5).
// ---------------------------------------------------------------------------
__global__ __launch_bounds__(256, 4) void conv_kernel(
    const u16* __restrict__ wbfT,  // [576 kflat8][512 co][8]
    const u16* __restrict__ xs,    // [16][32][32][512]
    const float* __restrict__ dsc, // [16][512]
    const u16* __restrict__ zp,    // >=16B zeros
    float* __restrict__ out)       // [16][512][32][32]
{
    __shared__ __align__(16) u16 lds[2 * 408 * 8];   // 2 x 6528 B

    const int tid  = threadIdx.x;
    const int lane = tid & 63;
    const int wv   = tid >> 6;       // 0..3  M-wave
    const int l31  = lane & 31;
    const int kc8  = lane >> 5;

    const int bx = blockIdx.x;       // 1024 blocks
    const int mt = bx & 1;           // cout half, pinned per XCD parity
    const int nt = bx >> 1;          // 0..511
    const int b  = nt >> 5;
    const int h0 = nt & 31;          // single output row

    const u16* xsb = xs + (size_t)b * (32 * 32 * 512);

    // ---- halo staging: 408 chunks = 102 p (3 rows x 34 cols) x 4 slots ----
    const u16* sb[2]; bool sval[2], inb[2];
#pragma unroll
    for (int k = 0; k < 2; ++k) {
        int ch = tid + k * 256;
        sval[k] = ch < 408;
        int p = ch >> 2, slot = ch & 3;
        int kc = slot ^ ((p >> 1) & 3);
        int rr = p / 34, cc = p % 34;
        int hh = h0 - 1 + rr, ww = cc - 1;
        inb[k] = sval[k] && ((unsigned)hh < 32u) && ((unsigned)ww < 32u);
        sb[k] = xsb + (hh * 32 + ww) * 512 + kc * 8;
    }
    char* ldsb = (char*)lds;

    auto stage = [&](int buf, int c0) {
        char* d = ldsb + buf * 6528 + wv * 1024;
        GLD16(inb[0] ? sb[0] + c0 : zp, d);
        if (sval[1]) GLD16(inb[1] ? sb[1] + c0 : zp, d + 4096);
    };

    // ---- A pointers: co = mt*256 + wv*64 + mf*32 + l31, kc-group kk*2+kc8 ----
    const u16* apb[2];
#pragma unroll
    for (int mf = 0; mf < 2; ++mf)
        apb[mf] = wbfT + ((size_t)kc8 * 512 + mt * 256 + wv * 64 + mf * 32 + l31) * 8;

    uint4 aA[2][2], aB[2][2];        // ping/pong [mf][kk]
    auto loadA = [&](uint4 (&dst)[2][2], int pos, int c0g) {
#pragma unroll
        for (int mf = 0; mf < 2; ++mf)
#pragma unroll
            for (int kk = 0; kk < 2; ++kk)
                dst[mf][kk] = *reinterpret_cast<const uint4*>(
                    apb[mf] + ((size_t)(pos * 64 + c0g) + kk * 2) * 4096);
    };

    // ---- B register ping-pong: [kk] (single nf) ----
    bf16x8 bvA[2], bvB[2];
    auto loadB = [&](bf16x8 (&dst)[2], const char* base, int pos) {
        const int kh = pos / 3, kw = pos % 3;
        const int p = kh * 34 + l31 + kw;
#pragma unroll
        for (int kk = 0; kk < 2; ++kk) {
            const int sk = kk * 2 + kc8;
            dst[kk] = *reinterpret_cast<const bf16x8*>(
                base + p * 64 + ((sk ^ ((p >> 1) & 3)) << 4));
        }
    };

    f32x16 acc[2] = {};
    auto domfma = [&](uint4 (&af)[2][2], bf16x8 (&bf)[2]) {
        __builtin_amdgcn_s_setprio(1);
#pragma unroll
        for (int kk = 0; kk < 2; ++kk)
#pragma unroll
            for (int mf = 0; mf < 2; ++mf) {
                bf16x8 av = *reinterpret_cast<const bf16x8*>(&af[mf][kk]);
                acc[mf] = __builtin_amdgcn_mfma_f32_32x32x16_bf16(
                    av, bf[kk], acc[mf], 0, 0, 0);
            }
        __builtin_amdgcn_s_setprio(0);
    };

    stage(0, 0);
    loadA(aA, 0, 0);
    __syncthreads();                 // one-time full drain: buf0 resident

    for (int r = 0; r < 16; ++r) {
        const int c0g = r * 4;
        const char* base = ldsb + (r & 1) * 6528;
        if (r < 15) stage((r + 1) & 1, (r + 1) * 32);   // flies over 9-tap phase
        loadB(bvA, base, 0);

#pragma unroll
        for (int pos = 0; pos < 9; ++pos) {
            if (pos < 8) {
                if ((pos & 1) == 0) { loadA(aB, pos + 1, c0g); loadB(bvB, base, pos + 1); }
                else                { loadA(aA, pos + 1, c0g); loadB(bvA, base, pos + 1); }
            } else if (r < 15) {
                loadA(aB, 0, c0g + 4);       // next round pos0 A
            }
            if ((pos & 1) == 0) domfma(aA, bvA);
            else                domfma(aB, bvB);
        }
        if (r < 15) {
#pragma unroll
            for (int mf = 0; mf < 2; ++mf)
#pragma unroll
                for (int kk = 0; kk < 2; ++kk) aA[mf][kk] = aB[mf][kk];
            // stage GLD16s are older than pos8's A-consume wait -> retired;
            // only the 4 next-pos0 A-loads remain in flight.
            asm volatile("s_waitcnt vmcnt(4)" ::: "memory");
            __builtin_amdgcn_s_barrier();
            asm volatile("" ::: "memory");
        }
    }

    // ---- epilogue: C/D col=lane&31, row=(q&3)+8*(q>>2)+4*(lane>>5) ----
    const float* db = dsc + b * 512;
#pragma unroll
    for (int mf = 0; mf < 2; ++mf) {
#pragma unroll
        for (int q = 0; q < 16; ++q) {
            int row = (q & 3) + 8 * (q >> 2) + 4 * kc8;
            int co  = mt * 256 + wv * 64 + mf * 32 + row;
            out[(((size_t)b * 512 + co) * 32 + h0) * 32 + l31]
                = acc[mf][q] * db[co];
        }
    }
}

// ---------------------------------------------------------------------------
extern "C" void kernel_launch(void* const* d_in, const int* in_sizes, int n_in,
                              void* d_out, int out_size, void* d_ws, size_t ws_size,
                              hipStream_t stream) {
    const float* x      = (const float*)d_in[0];
    const float* w      = (const float*)d_in[1];
    const float* mod_w  = (const float*)d_in[2];
    const float* mod_b  = (const float*)d_in[3];
    const float* ln_g   = (const float*)d_in[4];
    const float* ln_b   = (const float*)d_in[5];
    const float* weight = (const float*)d_in[6];
    const float* scale  = (const float*)d_in[7];
    float* out = (float*)d_out;

    char* ws = (char*)d_ws;
    float* s_raw = (float*)(ws);                     // 32 KB, reused as dsc
    float* dsc   = (float*)(ws);
    float* s_eff = (float*)(ws + 32768);             // 32 KB; head reused as zeros page
    float* wsq   = (float*)(ws + 65536);             // 1 MB
    u16*   wbfT  = (u16*)(ws + 65536 + 1048576);     // 4.5 MB
    u16*   xs    = (u16*)(ws + 65536 + 1048576 + 4718592);  // 16.78 MB
    if (ws_size < 22609920u) return;

    lin_kernel <<<2048, 256, 0, stream>>>(w, mod_w, mod_b, s_raw);
    wsq_kernel <<<1024, 256, 0, stream>>>(weight, wsq, wbfT);
    norm_kernel<<<16, 512, 0, stream>>>(s_raw, ln_g, ln_b, scale, s_eff);
    xs_kernel  <<<512, 256, 0, stream>>>(x, s_eff, xs);
    dsc_kernel <<<2048, 256, 0, stream>>>(s_eff, wsq, dsc);
    zfill_kernel<<<1, 1024, 0, stream>>>(s_eff);     // zeros page (s_eff dead now)
    conv_kernel<<<1024, 256, 0, stream>>>(wbfT, xs, dsc, (const u16*)s_eff, out);
}